// Round 9
// baseline (177.966 us; speedup 1.0000x reference)
//
#include <hip/hip_runtime.h>
#include <hip/hip_bf16.h>
#include <math.h>

// Problem constants
#define SEQ 4096
#define DM  1024
#define NIMU 72
#define NNOISE 12
#define NJ (NIMU*NNOISE)     // 864
#define TSTEPS 300
#define PLANE (NIMU*SEQ)     // 294912

// Fragment-linear layouts (16x16x32 bf16 MFMA operand granules):
//   granule(tile, ch) = 512 shorts; lane l holds 8 shorts at +l*8:
//     row = l&15 (m or n), k = ch*32 + (l>>4)*8 + 0..7
//   ch 0..31 = hi half (k 0..1023), ch 32..63 = lo half.
#define A2F_SHORTS ((size_t)256 * 64 * 512)
#define BTF_SHORTS ((size_t)56 * 64 * 512)

typedef __attribute__((ext_vector_type(8))) short bf16x8;
typedef __attribute__((ext_vector_type(4))) float f32x4;
typedef __attribute__((ext_vector_type(2))) float f32x2;

__device__ __forceinline__ float softplus_f(float x) {
    return fmaxf(x, 0.f) + log1pf(expf(-fabsf(x)));
}

// round-to-nearest-even bf16 split: x ~= hi + lo with |err| ~ 2^-16 * |x|
__device__ __forceinline__ void split_bf16(float x, short& hi, short& lo) {
    unsigned b = __float_as_uint(x);
    unsigned h = (b + 0x7FFFu + ((b >> 16) & 1u)) >> 16;
    float hf = __uint_as_float(h << 16);
    float r = x - hf;
    unsigned b2 = __float_as_uint(r);
    unsigned l2 = (b2 + 0x7FFFu + ((b2 >> 16) & 1u)) >> 16;
    hi = (short)h;
    lo = (short)l2;
}

// ---------------- 1. LayerNorm -> A2f (fragment-linear bf16 hi|lo) ----------------
__global__ __launch_bounds__(256) void ln_kernel(const float* __restrict__ x,
                                                 const float* __restrict__ gamma,
                                                 const float* __restrict__ beta,
                                                 short* __restrict__ A2f) {
    const int s_tile = blockIdx.x;
    const int tid = threadIdx.x;
    const int mrow = tid >> 4;      // row within s_tile
    const int g    = tid & 15;
    const int row  = s_tile * 16 + mrow;
    const float4* xr = (const float4*)(x + (size_t)row * DM);

    float s = 0.f, sq = 0.f;
    #pragma unroll
    for (int i = 0; i < 16; ++i) {
        float4 v = xr[g + 16 * i];
        s  += v.x + v.y + v.z + v.w;
        sq += v.x*v.x + v.y*v.y + v.z*v.z + v.w*v.w;
    }
    #pragma unroll
    for (int off = 1; off < 16; off <<= 1) {
        s  += __shfl_xor(s, off);
        sq += __shfl_xor(sq, off);
    }
    const float mean = s * (1.f / DM);
    const float var  = sq * (1.f / DM) - mean * mean;
    const float rstd = rsqrtf(fmaxf(var, 0.f) + 1e-5f);

    #pragma unroll
    for (int i = 0; i < 16; ++i) {
        float4 v = xr[g + 16 * i];
        float4 gm = ((const float4*)gamma)[g + 16 * i];
        float4 bt = ((const float4*)beta)[g + 16 * i];
        float o[4];
        o[0] = (v.x - mean) * rstd * gm.x + bt.x;
        o[1] = (v.y - mean) * rstd * gm.y + bt.y;
        o[2] = (v.z - mean) * rstd * gm.z + bt.z;
        o[3] = (v.w - mean) * rstd * gm.w + bt.w;
        short4 hv, lv;
        split_bf16(o[0], hv.x, lv.x);
        split_bf16(o[1], hv.y, lv.y);
        split_bf16(o[2], hv.z, lv.z);
        split_bf16(o[3], hv.w, lv.w);
        const int ch = (g >> 3) + 2 * i;
        const size_t base = ((size_t)s_tile * 64 + ch) * 512
                          + mrow * 8 + ((g >> 1) & 3) * 128 + (g & 1) * 4;
        *(short4*)(A2f + base)             = hv;   // hi: ch
        *(short4*)(A2f + base + 32 * 512)  = lv;   // lo: ch+32
    }
}

// ---------------- 2a. W -> Btf (transpose + split, fragment-linear) ----------------
__global__ __launch_bounds__(256) void wprep_kernel(const float* __restrict__ W,
                                                    short* __restrict__ Btf) {
    __shared__ float T[32][33];
    const int k0 = blockIdx.x * 32, j0 = blockIdx.y * 32;
    const int t = threadIdx.x;
    {
        const int r = t >> 3, c4 = (t & 7) * 4;
        float4 v = *(const float4*)(W + (size_t)(k0 + r) * NJ + j0 + c4);
        T[r][c4 + 0] = v.x; T[r][c4 + 1] = v.y; T[r][c4 + 2] = v.z; T[r][c4 + 3] = v.w;
    }
    __syncthreads();
    if (t < 128) {
        const int gq = t >> 6;          // which 16-j group
        const int l  = t & 63;
        const int n = l & 15, c = l >> 4;
        const int jt = blockIdx.y * 2 + gq;       // j_tile
        bf16x8 hv, lv;
        #pragma unroll
        for (int o = 0; o < 8; ++o) {
            short h, lo_;
            split_bf16(T[c * 8 + o][gq * 16 + n], h, lo_);
            hv[o] = h; lv[o] = lo_;
        }
        short* dh = Btf + ((size_t)jt * 64 + blockIdx.x) * 512 + l * 8;
        *(bf16x8*)dh = hv;
        *(bf16x8*)(dh + (size_t)32 * 512) = lv;   // lo chunk = ch+32
    }
}

// ---------------- 2b. Barrier-free MFMA GEMM + fused tail ----------------
// j < 576 (planes 0..7)  -> pt (spring inputs)
// j >= 576 (planes 8..11)-> out directly (acc/gyro base/std; softplus on odd planes)
__global__ __launch_bounds__(256, 1) void gemm_kernel(const short* __restrict__ A2f,
                                                      const short* __restrict__ Btf,
                                                      const float* __restrict__ bias,
                                                      float* __restrict__ pt,
                                                      float* __restrict__ out) {
    const int l = threadIdx.x & 63, w = threadIdx.x >> 6;
    const int st0 = blockIdx.x * 8 + (w & 1) * 4;    // wave's m-tile base
    const int jt0 = blockIdx.y * 8 + (w >> 1) * 4;   // wave's n-tile base
    const short* aB = A2f + (size_t)st0 * (64 * 512) + l * 8;
    const short* bB = Btf + (size_t)jt0 * (64 * 512) + l * 8;

    f32x4 acc[4][4] = {};
    bf16x8 ah[2][4], al[2][4], bh[2][4], bl[2][4];

    auto ldstep = [&](int slot, int i) {
        #pragma unroll
        for (int t = 0; t < 4; ++t) {
            ah[slot][t] = *(const bf16x8*)(aB + ((size_t)t * 64 + i) * 512);
            al[slot][t] = *(const bf16x8*)(aB + ((size_t)t * 64 + 32 + i) * 512);
            bh[slot][t] = *(const bf16x8*)(bB + ((size_t)t * 64 + i) * 512);
            bl[slot][t] = *(const bf16x8*)(bB + ((size_t)t * 64 + 32 + i) * 512);
        }
    };

    ldstep(0, 0);
    #pragma unroll 2
    for (int i = 0; i < 32; ++i) {
        const int cur = i & 1;
        if (i + 1 < 32) ldstep(cur ^ 1, i + 1);   // loads in flight during MFMA
        #pragma unroll
        for (int mi = 0; mi < 4; ++mi)
            #pragma unroll
            for (int ni = 0; ni < 4; ++ni)
                acc[mi][ni] = __builtin_amdgcn_mfma_f32_16x16x32_bf16(
                    ah[cur][mi], bh[cur][ni], acc[mi][ni], 0, 0, 0);
        #pragma unroll
        for (int mi = 0; mi < 4; ++mi)
            #pragma unroll
            for (int ni = 0; ni < 4; ++ni)
                acc[mi][ni] = __builtin_amdgcn_mfma_f32_16x16x32_bf16(
                    ah[cur][mi], bl[cur][ni], acc[mi][ni], 0, 0, 0);
        #pragma unroll
        for (int mi = 0; mi < 4; ++mi)
            #pragma unroll
            for (int ni = 0; ni < 4; ++ni)
                acc[mi][ni] = __builtin_amdgcn_mfma_f32_16x16x32_bf16(
                    al[cur][mi], bh[cur][ni], acc[mi][ni], 0, 0, 0);
    }

    // epilogue: C/D layout col=lane&15 (j-within-tile), row=(lane>>4)*4+reg (s)
    const int srow = (l >> 4) * 4;
    const int jcol = l & 15;
    #pragma unroll
    for (int ni = 0; ni < 4; ++ni) {
        const int j = (jt0 + ni) * 16 + jcol;
        if (j < NJ) {
            const float bj = bias[j];
            if (j < 8 * NIMU) {
                #pragma unroll
                for (int mi = 0; mi < 4; ++mi) {
                    f32x4 v = acc[mi][ni];
                    v[0] += bj; v[1] += bj; v[2] += bj; v[3] += bj;
                    *(f32x4*)(pt + (size_t)j * SEQ + (st0 + mi) * 16 + srow) = v;
                }
            } else {
                const int q  = (j - 8 * NIMU) / NIMU;          // plane 0..3
                const int im = (j - 8 * NIMU) - NIMU * q;
                float* dst = out + (size_t)(1 + q) * PLANE + (size_t)im * SEQ;
                #pragma unroll
                for (int mi = 0; mi < 4; ++mi) {
                    f32x4 v = acc[mi][ni];
                    v[0] += bj; v[1] += bj; v[2] += bj; v[3] += bj;
                    if (q & 1) {
                        v[0] = softplus_f(v[0]); v[1] = softplus_f(v[1]);
                        v[2] = softplus_f(v[2]); v[3] = softplus_f(v[3]);
                    }
                    *(f32x4*)(dst + (st0 + mi) * 16 + srow) = v;
                }
            }
        }
    }
}

// ---------------- 3. Spring recurrence + register diagonal scatter ----------------
// R8: 48.6us @ VALUBusy 82% but ~35 VALU/step (shfl wrapper + array regs + 5-op
// predication) and ragged grid (2304 > 2048 resident).
// R9: raw ds_bpermute with maintained byte-index regs (2 ops/step), B/C chunk
// accumulation (4 ops/step), scalarized batches, t-split x4 (chains 76/72),
// persistent grid 1536 blocks x exactly 3 tiles (uniform, 24 waves/CU).
#define NVTILE 4608   // 16 sblk x 72 imu x 4 tchunk
#define PGRID  1536

__global__ __launch_bounds__(256) void spring_kernel(const float* __restrict__ pt,
                                                     float* __restrict__ kin) {
    const int tid  = threadIdx.x;
    const int lane = tid & 63;
    const int wid  = tid >> 6;

    for (int vt = blockIdx.x; vt < NVTILE; vt += PGRID) {
        const int tc   = vt & 3;
        const int rr   = vt >> 2;
        const int imu  = rr % NIMU;
        const int sblk = rr / NIMU;
        const int tbeg = 76 * tc;
        const int tlen = (tc == 3) ? 72 : 76;
        const int sbase = sblk * 256 + (wid << 6);
        const int s    = sbase + lane;

        const int base = imu * SEQ + s;
        const float p0  = pt[(size_t)0 * PLANE + base];
        const float p1  = pt[(size_t)1 * PLANE + base];
        const float p2  = pt[(size_t)2 * PLANE + base];
        const float p3  = pt[(size_t)3 * PLANE + base];
        const float c1  = pt[(size_t)4 * PLANE + base];
        const float c2  = pt[(size_t)5 * PLANE + base];
        const float ph1 = pt[(size_t)6 * PLANE + base];
        const float ph2 = pt[(size_t)7 * PLANE + base];

        float dd = softplus_f(p1);
        float kk = dd * dd * 0.25f + softplus_f(p0);
        float om1 = 0.5f * sqrtf(fmaxf(4.f * kk - dd * dd, 0.f));
        float dt = softplus_f(p3);
        float kt = dt * dt * 0.25f + softplus_f(p2);
        float om2 = 0.5f * sqrtf(fmaxf(4.f * kt - dt * dt, 0.f));
        float e1 = expf(-0.5f * dd), e2 = expf(-0.5f * dt);
        float sn, cs, sn2, cs2;
        sincosf(om1, &sn, &cs);
        sincosf(om2, &sn2, &cs2);
        const f32x2 Rr = {e1 * cs, e2 * cs2};    // per-step rotation (osc1, osc2)
        const f32x2 Ri = {e1 * sn, e2 * sn2};
        sincosf(ph1, &sn, &cs);
        sincosf(ph2, &sn2, &cs2);
        f32x2 zr = {c1 * cs, c2 * cs2};          // state
        f32x2 zi = {c1 * sn, c2 * sn2};

        if (tbeg) {   // z *= R^tbeg, exp-by-squaring
            f32x2 prr = Rr, pri = Ri;
            f32x2 qr = {1.f, 1.f}, qi = {0.f, 0.f};
            int e = tbeg;
            while (e) {
                if (e & 1) {
                    f32x2 nr = qr * prr - qi * pri;
                    qi = qr * pri + qi * prr;
                    qr = nr;
                }
                f32x2 nr = prr * prr - pri * pri;
                pri = 2.f * prr * pri;
                prr = nr;
                e >>= 1;
            }
            f32x2 nr = zr * qr - zi * qi;
            zi = zr * qi + zi * qr;
            zr = nr;
        }

        float A0 = 0.f, A1 = 0.f, A2v = 0.f;
        int idx0 = ( lane      & 63) << 2;      // bpermute byte indices, rotate tr..tr+3
        int idx1 = ((lane - 1) & 63) << 2;
        int idx2 = ((lane - 2) & 63) << 2;
        int idx3 = ((lane - 3) & 63) << 2;

        const bool full = (sbase + 63 + tbeg + tlen - 1) < SEQ;   // wave-uniform
        const int tmax_lane = SEQ - s - tbeg;                      // for slow path

        #define ADV() { f32x2 nr_ = zr * Rr - zi * Ri;             \
                        zi = zr * Ri + zi * Rr; zr = nr_; }
        #define BPERM(u_, v_) u_ = __int_as_float(                 \
            __builtin_amdgcn_ds_bpermute(idx##u_##_, __float_as_int(v_)))

        #define CHUNK(AL, AH, TQ, TRMAX, MASKED)                                  \
        {                                                                         \
            float B = 0.f, C = 0.f;                                               \
            for (int tr0 = 0; tr0 < (TRMAX); tr0 += 4) {                          \
                float v0, v1, v2, v3;                                             \
                v0 = zi.x + zi.y;                                                 \
                if (MASKED) v0 = ((TQ)*64 + tr0 + 0 < tmax_lane) ? v0 : 0.f;      \
                ADV();                                                            \
                v1 = zi.x + zi.y;                                                 \
                if (MASKED) v1 = ((TQ)*64 + tr0 + 1 < tmax_lane) ? v1 : 0.f;      \
                ADV();                                                            \
                v2 = zi.x + zi.y;                                                 \
                if (MASKED) v2 = ((TQ)*64 + tr0 + 2 < tmax_lane) ? v2 : 0.f;      \
                ADV();                                                            \
                v3 = zi.x + zi.y;                                                 \
                if (MASKED) v3 = ((TQ)*64 + tr0 + 3 < tmax_lane) ? v3 : 0.f;      \
                ADV();                                                            \
                float u0 = __int_as_float(__builtin_amdgcn_ds_bpermute(idx0, __float_as_int(v0))); \
                float u1 = __int_as_float(__builtin_amdgcn_ds_bpermute(idx1, __float_as_int(v1))); \
                float u2 = __int_as_float(__builtin_amdgcn_ds_bpermute(idx2, __float_as_int(v2))); \
                float u3 = __int_as_float(__builtin_amdgcn_ds_bpermute(idx3, __float_as_int(v3))); \
                idx0 = (idx0 - 16) & 252; idx1 = (idx1 - 16) & 252;               \
                idx2 = (idx2 - 16) & 252; idx3 = (idx3 - 16) & 252;               \
                B += u0; C += (lane < tr0 + 0) ? u0 : 0.f;                        \
                B += u1; C += (lane < tr0 + 1) ? u1 : 0.f;                        \
                B += u2; C += (lane < tr0 + 2) ? u2 : 0.f;                        \
                B += u3; C += (lane < tr0 + 3) ? u3 : 0.f;                        \
            }                                                                     \
            AL += B - C; AH += C;                                                 \
        }

        const int trmax2 = tlen - 64;   // 12 or 8
        if (full) {
            CHUNK(A0, A1, 0, 64, 0)
            CHUNK(A1, A2v, 1, trmax2, 0)
        } else {
            CHUNK(A0, A1, 0, 64, 1)
            CHUNK(A1, A2v, 1, trmax2, 1)
        }
        #undef CHUNK
        #undef ADV

        // flush: A_r -> pos pbase + 64r + lane; A2v only lanes <= tlen-66
        const int pbase = sbase + tbeg;
        float* kimu = kin + (size_t)imu * SEQ;
        int pos = pbase + lane;
        if (pos < SEQ)
            __hip_atomic_fetch_add(kimu + pos, A0, __ATOMIC_RELAXED, __HIP_MEMORY_SCOPE_AGENT);
        pos += 64;
        if (pos < SEQ)
            __hip_atomic_fetch_add(kimu + pos, A1, __ATOMIC_RELAXED, __HIP_MEMORY_SCOPE_AGENT);
        pos += 64;
        if (lane <= tlen - 66 && pos < SEQ)
            __hip_atomic_fetch_add(kimu + pos, A2v, __ATOMIC_RELAXED, __HIP_MEMORY_SCOPE_AGENT);
    }
}

extern "C" void kernel_launch(void* const* d_in, const int* in_sizes, int n_in,
                              void* d_out, int out_size, void* d_ws, size_t ws_size,
                              hipStream_t stream) {
    const float* hs    = (const float*)d_in[0];
    const float* gamma = (const float*)d_in[1];
    const float* beta  = (const float*)d_in[2];
    const float* W     = (const float*)d_in[3];
    const float* b     = (const float*)d_in[4];
    float* out = (float*)d_out;

    short* A2f = (short*)d_ws;                        // 16.78 MB
    short* Btf = A2f + A2F_SHORTS;                    //  3.67 MB
    float* pt  = (float*)(Btf + BTF_SHORTS);          // 14.16 MB (planes 0..7 used)

    hipMemsetAsync(out, 0, (size_t)PLANE * sizeof(float), stream);

    ln_kernel<<<SEQ / 16, 256, 0, stream>>>(hs, gamma, beta, A2f);
    wprep_kernel<<<dim3(DM / 32, NJ / 32), 256, 0, stream>>>(W, Btf);
    gemm_kernel<<<dim3(SEQ / 128, 7), 256, 0, stream>>>(A2f, Btf, b, pt, out);
    spring_kernel<<<PGRID, 256, 0, stream>>>(pt, out);
}

// Round 11
// 163.561 us; speedup vs baseline: 1.0881x; 1.0881x over previous
//
#include <hip/hip_runtime.h>
#include <hip/hip_bf16.h>
#include <math.h>

// Problem constants
#define SEQ 4096
#define DM  1024
#define NIMU 72
#define NNOISE 12
#define NJ (NIMU*NNOISE)     // 864
#define TSTEPS 300
#define PLANE (NIMU*SEQ)     // 294912

// Fragment-linear layouts (16x16x32 bf16 MFMA operand granules):
//   granule(tile, ch) = 512 shorts; lane l holds 8 shorts at +l*8:
//     row = l&15 (m or n), k = ch*32 + (l>>4)*8 + 0..7
//   ch 0..31 = hi half (k 0..1023), ch 32..63 = lo half.
#define A2F_SHORTS ((size_t)256 * 64 * 512)
#define BTF_SHORTS ((size_t)56 * 64 * 512)

typedef __attribute__((ext_vector_type(8))) short bf16x8;
typedef __attribute__((ext_vector_type(4))) float f32x4;
typedef __attribute__((ext_vector_type(2))) float f32x2;

__device__ __forceinline__ float softplus_f(float x) {
    return fmaxf(x, 0.f) + log1pf(expf(-fabsf(x)));
}

// round-to-nearest-even bf16 split: x ~= hi + lo with |err| ~ 2^-16 * |x|
__device__ __forceinline__ void split_bf16(float x, short& hi, short& lo) {
    unsigned b = __float_as_uint(x);
    unsigned h = (b + 0x7FFFu + ((b >> 16) & 1u)) >> 16;
    float hf = __uint_as_float(h << 16);
    float r = x - hf;
    unsigned b2 = __float_as_uint(r);
    unsigned l2 = (b2 + 0x7FFFu + ((b2 >> 16) & 1u)) >> 16;
    hi = (short)h;
    lo = (short)l2;
}

// ---------------- 1. LayerNorm -> A2f (fragment-linear bf16 hi|lo) ----------------
__global__ __launch_bounds__(256) void ln_kernel(const float* __restrict__ x,
                                                 const float* __restrict__ gamma,
                                                 const float* __restrict__ beta,
                                                 short* __restrict__ A2f) {
    const int s_tile = blockIdx.x;
    const int tid = threadIdx.x;
    const int mrow = tid >> 4;      // row within s_tile
    const int g    = tid & 15;
    const int row  = s_tile * 16 + mrow;
    const float4* xr = (const float4*)(x + (size_t)row * DM);

    float s = 0.f, sq = 0.f;
    #pragma unroll
    for (int i = 0; i < 16; ++i) {
        float4 v = xr[g + 16 * i];
        s  += v.x + v.y + v.z + v.w;
        sq += v.x*v.x + v.y*v.y + v.z*v.z + v.w*v.w;
    }
    #pragma unroll
    for (int off = 1; off < 16; off <<= 1) {
        s  += __shfl_xor(s, off);
        sq += __shfl_xor(sq, off);
    }
    const float mean = s * (1.f / DM);
    const float var  = sq * (1.f / DM) - mean * mean;
    const float rstd = rsqrtf(fmaxf(var, 0.f) + 1e-5f);

    #pragma unroll
    for (int i = 0; i < 16; ++i) {
        float4 v = xr[g + 16 * i];
        float4 gm = ((const float4*)gamma)[g + 16 * i];
        float4 bt = ((const float4*)beta)[g + 16 * i];
        float o[4];
        o[0] = (v.x - mean) * rstd * gm.x + bt.x;
        o[1] = (v.y - mean) * rstd * gm.y + bt.y;
        o[2] = (v.z - mean) * rstd * gm.z + bt.z;
        o[3] = (v.w - mean) * rstd * gm.w + bt.w;
        short4 hv, lv;
        split_bf16(o[0], hv.x, lv.x);
        split_bf16(o[1], hv.y, lv.y);
        split_bf16(o[2], hv.z, lv.z);
        split_bf16(o[3], hv.w, lv.w);
        const int ch = (g >> 3) + 2 * i;
        const size_t base = ((size_t)s_tile * 64 + ch) * 512
                          + mrow * 8 + ((g >> 1) & 3) * 128 + (g & 1) * 4;
        *(short4*)(A2f + base)             = hv;   // hi: ch
        *(short4*)(A2f + base + 32 * 512)  = lv;   // lo: ch+32
    }
}

// ---------------- 2a. W -> Btf (transpose + split, fragment-linear) ----------------
__global__ __launch_bounds__(256) void wprep_kernel(const float* __restrict__ W,
                                                    short* __restrict__ Btf) {
    __shared__ float T[32][33];
    const int k0 = blockIdx.x * 32, j0 = blockIdx.y * 32;
    const int t = threadIdx.x;
    {
        const int r = t >> 3, c4 = (t & 7) * 4;
        float4 v = *(const float4*)(W + (size_t)(k0 + r) * NJ + j0 + c4);
        T[r][c4 + 0] = v.x; T[r][c4 + 1] = v.y; T[r][c4 + 2] = v.z; T[r][c4 + 3] = v.w;
    }
    __syncthreads();
    if (t < 128) {
        const int gq = t >> 6;          // which 16-j group
        const int l  = t & 63;
        const int n = l & 15, c = l >> 4;
        const int jt = blockIdx.y * 2 + gq;       // j_tile
        bf16x8 hv, lv;
        #pragma unroll
        for (int o = 0; o < 8; ++o) {
            short h, lo_;
            split_bf16(T[c * 8 + o][gq * 16 + n], h, lo_);
            hv[o] = h; lv[o] = lo_;
        }
        short* dh = Btf + ((size_t)jt * 64 + blockIdx.x) * 512 + l * 8;
        *(bf16x8*)dh = hv;
        *(bf16x8*)(dh + (size_t)32 * 512) = lv;   // lo chunk = ch+32
    }
}

// ---------------- 2b. Barrier-free MFMA GEMM + fused tail ----------------
// j < 576 (planes 0..7)  -> pt (spring inputs)
// j >= 576 (planes 8..11)-> out directly (acc/gyro base/std; softplus on odd planes)
__global__ __launch_bounds__(256, 1) void gemm_kernel(const short* __restrict__ A2f,
                                                      const short* __restrict__ Btf,
                                                      const float* __restrict__ bias,
                                                      float* __restrict__ pt,
                                                      float* __restrict__ out) {
    const int l = threadIdx.x & 63, w = threadIdx.x >> 6;
    const int st0 = blockIdx.x * 8 + (w & 1) * 4;    // wave's m-tile base
    const int jt0 = blockIdx.y * 8 + (w >> 1) * 4;   // wave's n-tile base
    const short* aB = A2f + (size_t)st0 * (64 * 512) + l * 8;
    const short* bB = Btf + (size_t)jt0 * (64 * 512) + l * 8;

    f32x4 acc[4][4] = {};
    bf16x8 ah[2][4], al[2][4], bh[2][4], bl[2][4];

    auto ldstep = [&](int slot, int i) {
        #pragma unroll
        for (int t = 0; t < 4; ++t) {
            ah[slot][t] = *(const bf16x8*)(aB + ((size_t)t * 64 + i) * 512);
            al[slot][t] = *(const bf16x8*)(aB + ((size_t)t * 64 + 32 + i) * 512);
            bh[slot][t] = *(const bf16x8*)(bB + ((size_t)t * 64 + i) * 512);
            bl[slot][t] = *(const bf16x8*)(bB + ((size_t)t * 64 + 32 + i) * 512);
        }
    };

    ldstep(0, 0);
    #pragma unroll 2
    for (int i = 0; i < 32; ++i) {
        const int cur = i & 1;
        if (i + 1 < 32) ldstep(cur ^ 1, i + 1);   // loads in flight during MFMA
        #pragma unroll
        for (int mi = 0; mi < 4; ++mi)
            #pragma unroll
            for (int ni = 0; ni < 4; ++ni)
                acc[mi][ni] = __builtin_amdgcn_mfma_f32_16x16x32_bf16(
                    ah[cur][mi], bh[cur][ni], acc[mi][ni], 0, 0, 0);
        #pragma unroll
        for (int mi = 0; mi < 4; ++mi)
            #pragma unroll
            for (int ni = 0; ni < 4; ++ni)
                acc[mi][ni] = __builtin_amdgcn_mfma_f32_16x16x32_bf16(
                    ah[cur][mi], bl[cur][ni], acc[mi][ni], 0, 0, 0);
        #pragma unroll
        for (int mi = 0; mi < 4; ++mi)
            #pragma unroll
            for (int ni = 0; ni < 4; ++ni)
                acc[mi][ni] = __builtin_amdgcn_mfma_f32_16x16x32_bf16(
                    al[cur][mi], bh[cur][ni], acc[mi][ni], 0, 0, 0);
    }

    // epilogue: C/D layout col=lane&15 (j-within-tile), row=(lane>>4)*4+reg (s)
    const int srow = (l >> 4) * 4;
    const int jcol = l & 15;
    #pragma unroll
    for (int ni = 0; ni < 4; ++ni) {
        const int j = (jt0 + ni) * 16 + jcol;
        if (j < NJ) {
            const float bj = bias[j];
            if (j < 8 * NIMU) {
                #pragma unroll
                for (int mi = 0; mi < 4; ++mi) {
                    f32x4 v = acc[mi][ni];
                    v[0] += bj; v[1] += bj; v[2] += bj; v[3] += bj;
                    *(f32x4*)(pt + (size_t)j * SEQ + (st0 + mi) * 16 + srow) = v;
                }
            } else {
                const int q  = (j - 8 * NIMU) / NIMU;          // plane 0..3
                const int im = (j - 8 * NIMU) - NIMU * q;
                float* dst = out + (size_t)(1 + q) * PLANE + (size_t)im * SEQ;
                #pragma unroll
                for (int mi = 0; mi < 4; ++mi) {
                    f32x4 v = acc[mi][ni];
                    v[0] += bj; v[1] += bj; v[2] += bj; v[3] += bj;
                    if (q & 1) {
                        v[0] = softplus_f(v[0]); v[1] = softplus_f(v[1]);
                        v[2] = softplus_f(v[2]); v[3] = softplus_f(v[3]);
                    }
                    *(f32x4*)(dst + (st0 + mi) * 16 + srow) = v;
                }
            }
        }
    }
}

// ---------------- 3. Spring: sliding-window rotate accumulator ----------------
// DPP recurrence a_l(t) = a_{l+1}(t-1) + v_l(t) using wave_shl1 (0x130: data
// shifts LEFT, dst lane l <- src lane l+1; bound_ctrl feeds 0 into lane 63).
// [R10 comment had the direction backwards: 0x138 wave_shr1 is l <- l-1.]
// Register a_l always holds the partial sum of ONE output position
// p = sbase + l + t; a_0(t) is the COMPLETE wave-local sum for p = sbase + t.
// Completed values collected into d via (lane==tr) select (tr = compile-time
// constant in the unrolled loop -> v_cmp+v_cndmask; __builtin_amdgcn_writelane
// does not exist in this ROCm). One coalesced wave-atomic flush per 64 steps.
// ~10 VALU issues/step vs R8's ~35 / R9's ~42.
__global__ __launch_bounds__(256) void spring_kernel(const float* __restrict__ pt,
                                                     float* __restrict__ kin) {
    const int lane = threadIdx.x & 63;
    const int wid  = threadIdx.x >> 6;
    const int sblk = blockIdx.x * 4 + wid;    // 0..63
    const int imu  = blockIdx.y;
    const int sbase = sblk * 64;
    const int s    = sbase + lane;

    const int base = imu * SEQ + s;
    const float p0  = pt[(size_t)0 * PLANE + base];
    const float p1  = pt[(size_t)1 * PLANE + base];
    const float p2  = pt[(size_t)2 * PLANE + base];
    const float p3  = pt[(size_t)3 * PLANE + base];
    const float c1  = pt[(size_t)4 * PLANE + base];
    const float c2  = pt[(size_t)5 * PLANE + base];
    const float ph1 = pt[(size_t)6 * PLANE + base];
    const float ph2 = pt[(size_t)7 * PLANE + base];

    float dd = softplus_f(p1);
    float kk = dd * dd * 0.25f + softplus_f(p0);
    float om1 = 0.5f * sqrtf(fmaxf(4.f * kk - dd * dd, 0.f));
    float dt = softplus_f(p3);
    float kt = dt * dt * 0.25f + softplus_f(p2);
    float om2 = 0.5f * sqrtf(fmaxf(4.f * kt - dt * dt, 0.f));
    float e1 = expf(-0.5f * dd), e2 = expf(-0.5f * dt);
    float sn, cs, sn2, cs2;
    sincosf(om1, &sn, &cs);
    sincosf(om2, &sn2, &cs2);
    const f32x2 Rr = {e1 * cs, e2 * cs2};    // per-step rotation (osc1, osc2)
    const f32x2 Ri = {e1 * sn, e2 * sn2};
    sincosf(ph1, &sn, &cs);
    sincosf(ph2, &sn2, &cs2);
    f32x2 zr = {c1 * cs, c2 * cs2};          // state
    f32x2 zi = {c1 * sn, c2 * sn2};

    float a = 0.f;   // sliding accumulator: holds p = sbase + lane + t
    float d = 0.f;   // finished-value collector: lane tr holds p = sbase + 64q + tr
    float* kimu = kin + (size_t)imu * SEQ;

    #pragma unroll
    for (int q = 0; q < 5; ++q) {
        const int steps = (q == 4) ? 44 : 64;   // 300 = 4*64 + 44
        #pragma unroll
        for (int tr = 0; tr < steps; ++tr) {
            float v = zi.x + zi.y;                        // Im(z1)+Im(z2) at step t
            f32x2 nr = zr * Rr - zi * Ri;                 // z *= R (packed)
            zi = zr * Ri + zi * Rr;
            zr = nr;
            // a = wave_shl1(a) + v   (lane l <- lane l+1; 0 into lane 63)
            int as = __builtin_amdgcn_update_dpp(0, __float_as_int(a),
                                                 0x130, 0xF, 0xF, true);
            a = __int_as_float(as) + v;
            // capture completed position p = sbase + 64q + tr from lane 0
            int u = __builtin_amdgcn_readlane(__float_as_int(a), 0);
            d = (lane == tr) ? __int_as_float(u) : d;
        }
        const int pos = sbase + q * 64 + lane;   // q=4: lanes 44..63 add 0 (d reset)
        if (pos < SEQ)
            __hip_atomic_fetch_add(kimu + pos, d,
                                   __ATOMIC_RELAXED, __HIP_MEMORY_SCOPE_AGENT);
        d = 0.f;
    }

    // tail: a_l holds p = sbase + 299 + l for l>=1 (l=0 already captured at t=299)
    if (lane > 0) {
        const int pos = sbase + 299 + lane;
        if (pos < SEQ)
            __hip_atomic_fetch_add(kimu + pos, a,
                                   __ATOMIC_RELAXED, __HIP_MEMORY_SCOPE_AGENT);
    }
}

extern "C" void kernel_launch(void* const* d_in, const int* in_sizes, int n_in,
                              void* d_out, int out_size, void* d_ws, size_t ws_size,
                              hipStream_t stream) {
    const float* hs    = (const float*)d_in[0];
    const float* gamma = (const float*)d_in[1];
    const float* beta  = (const float*)d_in[2];
    const float* W     = (const float*)d_in[3];
    const float* b     = (const float*)d_in[4];
    float* out = (float*)d_out;

    short* A2f = (short*)d_ws;                        // 16.78 MB
    short* Btf = A2f + A2F_SHORTS;                    //  3.67 MB
    float* pt  = (float*)(Btf + BTF_SHORTS);          // 14.16 MB (planes 0..7 used)

    (void)hipMemsetAsync(out, 0, (size_t)PLANE * sizeof(float), stream);

    ln_kernel<<<SEQ / 16, 256, 0, stream>>>(hs, gamma, beta, A2f);
    wprep_kernel<<<dim3(DM / 32, NJ / 32), 256, 0, stream>>>(W, Btf);
    gemm_kernel<<<dim3(SEQ / 128, 7), 256, 0, stream>>>(A2f, Btf, b, pt, out);
    spring_kernel<<<dim3(16, NIMU), 256, 0, stream>>>(pt, out);
}